// Round 8
// baseline (203.017 us; speedup 1.0000x reference)
//
#include <hip/hip_runtime.h>
#include <math.h>

typedef float vf4 __attribute__((ext_vector_type(4)));
typedef float f32x4 __attribute__((ext_vector_type(4)));
typedef short bf16x8 __attribute__((ext_vector_type(8)));
typedef short short4v __attribute__((ext_vector_type(4)));
typedef int int2v __attribute__((ext_vector_type(2)));
typedef int int4v __attribute__((ext_vector_type(4)));

constexpr int B = 2, T = 2048, E = 512, NH = 8, HD = 64;
constexpr int BH = B * NH;            // 16
constexpr int NT = BH * T;            // 32768
constexpr int KSPLIT = 4;
constexpr float SCALE = 0.125f;       // HD^-0.5
constexpr float LOG2E = 1.44269504088896f;
constexpr float QSC = SCALE * LOG2E;  // folded into Q -> S in log2 domain

static __device__ __forceinline__ short f2bf(float f) {
  unsigned u = __float_as_uint(f);
  unsigned r = (u + 0x7fffu + ((u >> 16) & 1u)) >> 16;   // RNE
  return (short)r;
}
static __device__ __forceinline__ unsigned pk2bf(float a, float b) {  // RNE pack
  unsigned lo = (unsigned)(unsigned short)f2bf(a);
  unsigned hi = (unsigned)(unsigned short)f2bf(b);
  return lo | (hi << 16);
}
// cheap half-up bf16 pack (unbiased, <=2^-9 rel err) — inner-loop use
static __device__ __forceinline__ unsigned pkhu(float a, float b) {
  unsigned ua = __float_as_uint(a) + 0x8000u;
  unsigned ub = __float_as_uint(b) + 0x8000u;
  return __builtin_amdgcn_perm(ub, ua, 0x07060302u);  // [ua.hi16 | ub.hi16]
}
#if __has_builtin(__builtin_amdgcn_exp2f)
#define EXP2F(x) __builtin_amdgcn_exp2f(x)
#else
#define EXP2F(x) exp2f(x)
#endif
static __device__ __forceinline__ float bf2f(short s) {
  return __uint_as_float(((unsigned)(unsigned short)s) << 16);
}

// =====================================================================
// prep_all: fused cast_x | w_qkv^T | w_out^T | w_comb.  Grid 3105 blocks.
// =====================================================================
__global__ __launch_bounds__(256) void prep_all(
    const float* __restrict__ x, const float* __restrict__ w_qkv,
    const float* __restrict__ b_qkv, const float* __restrict__ w_od,
    const float* __restrict__ b_od,
    short* __restrict__ xb, short* __restrict__ wTq, short* __restrict__ wTo,
    const float* __restrict__ w_out, float* __restrict__ Wc,
    float* __restrict__ bc)
{
  __shared__ float sh[8464];
  const int bid = blockIdx.x;
  const int tid = threadIdx.x;

  if (bid < 2048) {                       // ---- cast x -> bf16
    int idx = (bid * 256 + tid) * 4;
    vf4 v = *(const vf4*)&x[idx];
    short4v o;
    o[0] = f2bf(v[0]); o[1] = f2bf(v[1]); o[2] = f2bf(v[2]); o[3] = f2bf(v[3]);
    *(short4v*)&xb[idx] = o;
  } else if (bid < 3072) {                // ---- transpose-cast weights
    const float* w; short* wT; int N, t;
    if (bid < 2816) { t = bid - 2048; w = w_qkv; wT = wTq; N = 1536; }
    else            { t = bid - 2816; w = w_out; wT = wTo; N = 512; }
    float (*tt)[33] = (float(*)[33])sh;
    const int k0 = (t & 15) * 32;
    const int n0 = (t >> 4) * 32;
    const int c = tid & 31, r = tid >> 5;  // r: 0..7
#pragma unroll
    for (int p = 0; p < 4; ++p)
      tt[r + p * 8][c] = w[(size_t)(k0 + r + p * 8) * N + n0 + c];
    __syncthreads();
#pragma unroll
    for (int p = 0; p < 4; ++p)
      wT[(size_t)(n0 + r + p * 8) * 512 + k0 + c] = f2bf(tt[c][r + p * 8]);
  } else {                                // ---- w_comb
    float* Lod = sh;                 // 512*16
    float (*pb)[17] = (float(*)[17])(sh + 8192);
    const int bx = bid - 3072;       // 0..32
#pragma unroll
    for (int p = 0; p < 8; ++p) {
      int idx = (p * 256 + tid) * 4;
      *(vf4*)&Lod[idx] = *(const vf4*)&w_od[idx];
    }
    __syncthreads();
    if (bx < 32) {
      const int k = bx * 16 + (tid >> 4);
      const int c = tid & 15;
      float s = 0.0f;
      for (int m = 0; m < E; m += 4) {
        vf4 wq = *(const vf4*)&w_qkv[(size_t)k * 1536 + m];
        s += wq[0] * Lod[(m + 0) * 16 + c] + wq[1] * Lod[(m + 1) * 16 + c]
           + wq[2] * Lod[(m + 2) * 16 + c] + wq[3] * Lod[(m + 3) * 16 + c];
      }
      Wc[k * 16 + c] = s;
    } else {
      const int c = tid & 15, seg = tid >> 4;
      float s = 0.0f;
      for (int m = seg * 32; m < seg * 32 + 32; ++m)
        s += b_qkv[m] * Lod[m * 16 + c];
      pb[seg][c] = s;
      __syncthreads();
      if (tid < 16) {
        float acc = b_od[tid];
#pragma unroll
        for (int g = 0; g < 16; ++g) acc += pb[g][tid];
        bc[tid] = acc;
      }
    }
  }
}

// =====================================================================
// Fused qkv GEMM + od/window-params.  Grid 1024: blocks 0..767 GEMM
// (128x64 tiles, BK=32, double-buffered, 1 barrier/iter); 768..1023 od.
// =====================================================================
__global__ __launch_bounds__(256) void qkv_od(
    const short* __restrict__ xb, const short* __restrict__ wT,
    const float* __restrict__ bias, short* __restrict__ qkvb,
    short* __restrict__ Vtg,
    const float* __restrict__ x, const float* __restrict__ Wc,
    const float* __restrict__ bc, float* __restrict__ prm)
{
  __shared__ __align__(16) short smem_s[16896];   // 33792 B
  const int bid = blockIdx.x;
  const int tid = threadIdx.x;

  if (bid < 768) {
    // ---------------- qkv GEMM 128x64, dbuf ----------------
    const int wave = tid >> 6, lane = tid & 63;
    const int quad = lane >> 4, l15 = lane & 15;
    const int wm = wave >> 1, wn = wave & 1;
    const int bx = bid % 24, by = bid / 24;
    const int m0 = by * 128, n0 = bx * 64;

    f32x4 acc[4][2];
#pragma unroll
    for (int mi = 0; mi < 4; ++mi)
#pragma unroll
      for (int ni = 0; ni < 2; ++ni) acc[mi][ni] = (f32x4){0, 0, 0, 0};

    const int sr = tid >> 1, sc = (tid & 1) * 16;     // A: 128 x 32
    const int br2 = tid >> 2, bk2 = (tid & 3) * 8;    // B: 64 x 32

#define QLD(R, K0) do {                                                   \
      R[0] = *(const bf16x8*)&xb[(size_t)(m0 + sr) * 512 + (K0) + sc];    \
      R[1] = *(const bf16x8*)&xb[(size_t)(m0 + sr) * 512 + (K0) + sc + 8];\
      R[2] = *(const bf16x8*)&wT[(size_t)(n0 + br2) * 512 + (K0) + bk2];  \
    } while (0)
#define QST(BUF, R) do {                                                  \
      short* As_ = smem_s + (BUF) * 7680;                                 \
      short* Bt_ = As_ + 5120;                                            \
      *(bf16x8*)&As_[sr * 40 + sc] = R[0];                                \
      *(bf16x8*)&As_[sr * 40 + sc + 8] = R[1];                            \
      *(bf16x8*)&Bt_[br2 * 40 + bk2] = R[2];                              \
    } while (0)
#define QMM(BUF) do {                                                     \
      const short* As_ = smem_s + (BUF) * 7680;                           \
      const short* Bt_ = As_ + 5120;                                      \
      bf16x8 aA[4], bB[2];                                                \
      for (int mi = 0; mi < 4; ++mi)                                      \
        aA[mi] = *(const bf16x8*)&As_[(wm * 64 + mi * 16 + l15) * 40 + quad * 8]; \
      for (int ni = 0; ni < 2; ++ni)                                      \
        bB[ni] = *(const bf16x8*)&Bt_[(wn * 32 + ni * 16 + l15) * 40 + quad * 8]; \
      for (int mi = 0; mi < 4; ++mi)                                      \
        for (int ni = 0; ni < 2; ++ni)                                    \
          acc[mi][ni] = __builtin_amdgcn_mfma_f32_16x16x32_bf16(          \
              aA[mi], bB[ni], acc[mi][ni], 0, 0, 0);                      \
    } while (0)

    bf16x8 rA[3], rB[3];
    QLD(rA, 0); QST(0, rA);
    QLD(rA, 32);
    __syncthreads();
#pragma unroll 1
    for (int k0 = 0; k0 < 512; k0 += 64) {
      if (k0 + 64 < 512) QLD(rB, k0 + 64);
      QMM(0);
      QST(1, rA);
      __syncthreads();
      if (k0 + 96 < 512) QLD(rA, k0 + 96);
      QMM(1);
      if (k0 + 64 < 512) { QST(0, rB); __syncthreads(); }
    }
#undef QLD
#undef QST
#undef QMM

#pragma unroll
    for (int mi = 0; mi < 4; ++mi)
#pragma unroll
      for (int ni = 0; ni < 2; ++ni) {
        const int col = n0 + wn * 32 + ni * 16 + l15;
        const int rowb = m0 + wm * 64 + mi * 16 + quad * 4;
        const float bs = bias[col];
        if (col < 1024) {
          const float qs = (col < 512) ? QSC : 1.0f;
#pragma unroll
          for (int r = 0; r < 4; ++r)
            qkvb[(size_t)(rowb + r) * 1536 + col] =
                f2bf((acc[mi][ni][r] + bs) * qs);
        } else {
          // V: transposed write  Vtg[(b*8+h)*64+hd][t]
          const int h = (col - 1024) >> 6, hd = col & 63;
          const int b = rowb >> 11, tt = rowb & 2047;
          int2v pk;
          pk[0] = (int)pk2bf(acc[mi][ni][0] + bs, acc[mi][ni][1] + bs);
          pk[1] = (int)pk2bf(acc[mi][ni][2] + bs, acc[mi][ni][3] + bs);
          *(int2v*)&Vtg[(size_t)(((b << 3) + h) * 64 + hd) * T + tt] = pk;
        }
      }
  } else {
    // ---------------- od + window params (fp32 exact) ----------------
    float* Lod = (float*)smem_s;            // 8192 floats (Wc staged)
    float* ods = ((float*)smem_s) + 8192;   // 16x16
    const int obx = bid - 768;
#pragma unroll
    for (int p = 0; p < 8; ++p) {
      int idx = (p * 256 + tid) * 4;
      *(vf4*)&Lod[idx] = *(const vf4*)&Wc[idx];
    }
    __syncthreads();

    const int r = tid >> 4, c = tid & 15;
    const int row = obx * 16 + r;
    float sum = bc[c];
    const float* qr = x + (size_t)row * E;
    for (int k = 0; k < E; k += 4) {
      vf4 q = *(const vf4*)&qr[k];
      sum += q[0] * Lod[(k + 0) * 16 + c]
           + q[1] * Lod[(k + 1) * 16 + c]
           + q[2] * Lod[(k + 2) * 16 + c]
           + q[3] * Lod[(k + 3) * 16 + c];
    }
    ods[r * 16 + c] = sum;
    __syncthreads();

    if (tid < 128) {
      const int rr = tid >> 3, h = tid & 7;
      const int grow = obx * 16 + rr;
      const int b = grow / T, i = grow % T;
      float o = ods[rr * 16 + h];
      float d = ods[rr * 16 + h + 8];
      float offset   = tanhf(o) * (float)T;
      float duration = (float)T / (1.0f + expf(-d));
      float anchor = (float)i + offset;
      float start = anchor - duration;
      float end   = anchor + duration;
      float bl = floorf(start);
      float br = ceilf(end);
      float al = floorf(anchor);
      float wbl = bl - start;
      float wbr = end - br;
      float af  = anchor - al;
      float rsc = 1.0f;
      if (br < 0.0f || bl > (float)(T - 1)) {
        bl = 0.0f; br = (float)(T - 1);
        wbl = 0.0f; wbr = 0.0f; al = -5.0f; af = 0.0f;
        rsc = 0.0f;
      }
      int idx = (b * NH + h) * T + i;
      prm[0 * NT + idx] = bl;
      prm[1 * NT + idx] = br;
      prm[2 * NT + idx] = wbl;
      prm[3 * NT + idx] = wbr;
      prm[4 * NT + idx] = al;
      prm[5 * NT + idx] = af;
      prm[6 * NT + idx] = rsc;
    }
  }
}

// =====================================================================
// MFMA flash attention: transposed-S, log2-domain, K-split 4-way,
// LDS dbuf + 2-deep register prefetch (one barrier/tile), l summed by
// a ones-fragment MFMA sharing the PV B-operand. Opart bf16.
// =====================================================================
__global__ __launch_bounds__(256, 4) void flash_attn_mfma6(
    const short* __restrict__ qkvb, const short* __restrict__ Vtg,
    const float* __restrict__ prm,
    short* __restrict__ Opart, float* __restrict__ lpart)
{
  __shared__ __align__(16) short Ks[2][64 * 72];
  __shared__ __align__(16) short Vt[2][64 * 72];
  __shared__ __align__(16) short Ps[4][16 * 72];
  __shared__ float u_s[8];

  const int tid = threadIdx.x;
  const int wave = tid >> 6, lane = tid & 63;
  const int quad = lane >> 4, l15 = lane & 15;
  const int qt = blockIdx.x, bh = blockIdx.y, ks = blockIdx.z;
  const int b = bh >> 3, h = bh & 7;
  const int i0 = qt * 64;
  const int i = i0 + wave * 16 + l15;          // this lane's query row

  const int pidx = bh * T + i;
  float blf = prm[0 * NT + pidx];
  float brf = prm[1 * NT + pidx];
  float wbl = prm[2 * NT + pidx];
  float wbr = prm[3 * NT + pidx];
  float alf = prm[4 * NT + pidx];
  float afr = prm[5 * NT + pidx];
  float rsc = prm[6 * NT + pidx];
  const int bli = (int)blf, widi = (int)brf - bli, ali = (int)alf;
  const unsigned widu = (unsigned)widi;
  const float a1 = 1.0f - afr;

  // Q fragment (B-frag: lane = i, regs = hd); zeroed for degenerate rows
  bf16x8 aQ0, aQ1;
  {
    size_t bq = (size_t)(b * T + i) * 1536 + h * 64;
    aQ0 = *(const bf16x8*)&qkvb[bq + quad * 8];
    aQ1 = *(const bf16x8*)&qkvb[bq + 32 + quad * 8];
    if (rsc == 0.0f) {
      bf16x8 z = {0, 0, 0, 0, 0, 0, 0, 0};
      aQ0 = z; aQ1 = z;
    }
  }

  // block union of windows -> K-tile range for this split
  float bmn = blf, bmx = brf;
#pragma unroll
  for (int d = 1; d < 64; d <<= 1) {
    bmn = fminf(bmn, __shfl_xor(bmn, d));
    bmx = fmaxf(bmx, __shfl_xor(bmx, d));
  }
  if (lane == 0) { u_s[wave * 2] = bmn; u_s[wave * 2 + 1] = bmx; }
  __syncthreads();
  bmn = fminf(fminf(u_s[0], u_s[2]), fminf(u_s[4], u_s[6]));
  bmx = fmaxf(fmaxf(u_s[1], u_s[3]), fmaxf(u_s[5], u_s[7]));
  const int ktlo = max(ks * 8, max(((int)bmn) >> 6, 0));
  const int kthi = min(ks * 8 + 7, min(((int)bmx) >> 6, T / 64 - 1));

  f32x4 o[4];
#pragma unroll
  for (int c = 0; c < 4; ++c) o[c] = (f32x4){0, 0, 0, 0};
  f32x4 lq = (f32x4){0, 0, 0, 0};
  const short BF1 = (short)0x3F80;
  const bf16x8 vone = {BF1, BF1, BF1, BF1, BF1, BF1, BF1, BF1};

  const int rq = tid >> 3, cb = (tid & 7) * 8;
  const short* kbase = qkvb + (size_t)b * T * 1536 + 512 + h * 64 + cb;
  const short* vbase = Vtg + (size_t)bh * 64 * T + cb;

#define FLD(R, KT) do { int j_ = (KT) * 64;                              \
    R[0] = *(const bf16x8*)&kbase[(size_t)(j_ + rq) * 1536];             \
    R[1] = *(const bf16x8*)&kbase[(size_t)(j_ + 32 + rq) * 1536];        \
    R[2] = *(const bf16x8*)&vbase[(size_t)rq * T + j_];                  \
    R[3] = *(const bf16x8*)&vbase[(size_t)(32 + rq) * T + j_];           \
  } while (0)
#define FST(BUF, R) do {                                                 \
    *(bf16x8*)&Ks[BUF][rq * 72 + cb] = R[0];                             \
    *(bf16x8*)&Ks[BUF][(32 + rq) * 72 + cb] = R[1];                      \
    *(bf16x8*)&Vt[BUF][rq * 72 + cb] = R[2];                             \
    *(bf16x8*)&Vt[BUF][(32 + rq) * 72 + cb] = R[3];                      \
  } while (0)

  auto compute = [&](int bufc, int ktc) {
    const int j0 = ktc * 64;
    const short* KsB = Ks[bufc];
    const short* VtB = Vt[bufc];

    // ---- S^T = K Q^T (log2 domain): regs = j, lane = i ----
    f32x4 s[4];
#pragma unroll
    for (int nc = 0; nc < 4; ++nc) {
      const short* kb = &KsB[(nc * 16 + l15) * 72 + quad * 8];
      f32x4 a = (f32x4){0, 0, 0, 0};
      a = __builtin_amdgcn_mfma_f32_16x16x32_bf16(*(const bf16x8*)&kb[0],  aQ0, a, 0, 0, 0);
      a = __builtin_amdgcn_mfma_f32_16x16x32_bf16(*(const bf16x8*)&kb[32], aQ1, a, 0, 0, 0);
      s[nc] = a;
    }

    // interior tile for every row of this wave? (wave-uniform branch)
    const int clean = (bli < j0) & (bli + widi > j0 + 63) &
                      ((ali > j0 + 63) | (ali + 1 < j0));
    if (__all(clean)) {
#pragma unroll
      for (int nc = 0; nc < 4; ++nc) {
        float p0 = EXP2F(s[nc][0]);
        float p1 = EXP2F(s[nc][1]);
        float p2 = EXP2F(s[nc][2]);
        float p3 = EXP2F(s[nc][3]);
        int2v pk;
        pk[0] = (int)pkhu(p0, p1);
        pk[1] = (int)pkhu(p2, p3);
        *(int2v*)&Ps[wave][l15 * 72 + nc * 16 + quad * 4] = pk;
      }
    } else {
      const int dq  = j0 + quad * 4 - bli;
      const int dq2 = j0 + quad * 4 - ali;
#pragma unroll
      for (int nc = 0; nc < 4; ++nc) {
        const int dn = dq + nc * 16, d2n = dq2 + nc * 16;
        float pr[4];
#pragma unroll
        for (int r = 0; r < 4; ++r) {
          int d = dn + r, d2 = d2n + r;
          float e  = (d == 0) ? wbl : ((d == widi) ? wbr : 0.0f);
          float aw = (d2 == 0) ? a1 : ((d2 == 1) ? afr : 0.0f);
          float w = 1.0f + e + aw;
          float v = s[nc][r] * w;                    // log2 domain
          v = ((unsigned)d <= widu) ? v : -115.0f;
          pr[r] = EXP2F(v);
        }
        int2v pk;
        pk[0] = (int)pkhu(pr[0], pr[1]);
        pk[1] = (int)pkhu(pr[2], pr[3]);
        *(int2v*)&Ps[wave][l15 * 72 + nc * 16 + quad * 4] = pk;
      }
    }
    // wave-private Ps: no barrier needed

    // ---- O^T += V^T P^T ; l += ones^T P^T ----
    bf16x8 bP0 = *(const bf16x8*)&Ps[wave][l15 * 72 + quad * 8];
    bf16x8 bP1 = *(const bf16x8*)&Ps[wave][l15 * 72 + 32 + quad * 8];
    lq = __builtin_amdgcn_mfma_f32_16x16x32_bf16(vone, bP0, lq, 0, 0, 0);
    lq = __builtin_amdgcn_mfma_f32_16x16x32_bf16(vone, bP1, lq, 0, 0, 0);
#pragma unroll
    for (int nc2 = 0; nc2 < 4; ++nc2) {
      const short* vb = &VtB[(nc2 * 16 + l15) * 72 + quad * 8];
      o[nc2] = __builtin_amdgcn_mfma_f32_16x16x32_bf16(
          *(const bf16x8*)&vb[0],  bP0, o[nc2], 0, 0, 0);
      o[nc2] = __builtin_amdgcn_mfma_f32_16x16x32_bf16(
          *(const bf16x8*)&vb[32], bP1, o[nc2], 0, 0, 0);
    }
  };

  if (ktlo <= kthi) {
    bf16x8 rA[4], rB[4];
    FLD(rA, ktlo);
    FST(0, rA);
    if (ktlo + 1 <= kthi) FLD(rA, ktlo + 1);
    __syncthreads();
    int buf = 0, kt = ktlo;
    while (true) {
      if (kt + 2 <= kthi) FLD(rB, kt + 2);
      compute(buf, kt);
      if (kt == kthi) break;
      FST(buf ^ 1, rA);
      __syncthreads();
      buf ^= 1; ++kt;
      if (kt + 2 <= kthi) FLD(rA, kt + 2);
      compute(buf, kt);
      if (kt == kthi) break;
      FST(buf ^ 1, rB);
      __syncthreads();
      buf ^= 1; ++kt;
    }
  }
#undef FLD
#undef FST

  // l: every lane's lq[0] already holds the full row-sum for its i
  if (lane < 16)
    lpart[ks * NT + bh * T + i] = lq[0];

  // O^T epilogue (bf16): lane = row i, regs = channels c
  size_t ob = (size_t)ks * (B * T * E) + (size_t)(b * T + i) * E + h * 64;
#pragma unroll
  for (int nc2 = 0; nc2 < 4; ++nc2) {
    int2v pk;
    pk[0] = (int)pk2bf(o[nc2][0], o[nc2][1]);
    pk[1] = (int)pk2bf(o[nc2][2], o[nc2][3]);
    *(int2v*)&Opart[ob + nc2 * 16 + quad * 4] = pk;
  }
}

// =====================================================================
// attn = sum_s O_s / sum_s l_s, bf16 in/out. 8 elems/thread.
// =====================================================================
__global__ __launch_bounds__(256) void combine_attn(
    const short* __restrict__ Opart, const float* __restrict__ lpart,
    short* __restrict__ attnb)
{
  int base = (blockIdx.x * 256 + threadIdx.x) * 8;
  int row = base >> 9;            // / 512
  int c = base & 511;
  int h = c >> 6;
  int b = row >> 11;              // / T
  int i = row & (T - 1);
  int lidx = ((b << 3) + h) * T + i;
  float l = (lpart[lidx] + lpart[NT + lidx]) +
            (lpart[2 * NT + lidx] + lpart[3 * NT + lidx]);
  float inv = 1.0f / l;
  bf16x8 o0 = *(const bf16x8*)&Opart[base];
  bf16x8 o1 = *(const bf16x8*)&Opart[(size_t)(B * T * E) + base];
  bf16x8 o2 = *(const bf16x8*)&Opart[(size_t)(2 * B * T * E) + base];
  bf16x8 o3 = *(const bf16x8*)&Opart[(size_t)(3 * B * T * E) + base];
  int4v ov;
#pragma unroll
  for (int j = 0; j < 4; ++j) {
    float a = ((bf2f(o0[2 * j]) + bf2f(o1[2 * j])) +
               (bf2f(o2[2 * j]) + bf2f(o3[2 * j]))) * inv;
    float bb = ((bf2f(o0[2 * j + 1]) + bf2f(o1[2 * j + 1])) +
                (bf2f(o2[2 * j + 1]) + bf2f(o3[2 * j + 1]))) * inv;
    ov[j] = (int)pk2bf(a, bb);
  }
  *(int4v*)&attnb[base] = ov;
}

// =====================================================================
// out GEMM (bf16 MFMA): out[4096][512] = attnb @ w_out + b_out (fp32).
// Tile 64x64, BK=32, dbuf (1 barrier/iter). Grid (8, 64) = 512 blocks.
// =====================================================================
__global__ __launch_bounds__(256) void out_gemm_bf16(
    const short* __restrict__ Ab, const short* __restrict__ wT,
    const float* __restrict__ bias, float* __restrict__ Co)
{
  __shared__ __align__(16) short smem_o[10240];   // 2 bufs x (64*40 + 64*40)

  const int tid = threadIdx.x;
  const int wave = tid >> 6, lane = tid & 63;
  const int quad = lane >> 4, l15 = lane & 15;
  const int wm = wave >> 1, wn = wave & 1;
  const int m0 = blockIdx.y * 64, n0 = blockIdx.x * 64;

  f32x4 acc[2][2];
#pragma unroll
  for (int mi = 0; mi < 2; ++mi)
#pragma unroll
    for (int ni = 0; ni < 2; ++ni) acc[mi][ni] = (f32x4){0, 0, 0, 0};

  const int ar = tid >> 2, akc = (tid & 3) * 8;

#define OLD(R, K0) do {                                                  \
    R[0] = *(const bf16x8*)&Ab[(size_t)(m0 + ar) * 512 + (K0) + akc];    \
    R[1] = *(const bf16x8*)&wT[(size_t)(n0 + ar) * 512 + (K0) + akc];    \
  } while (0)
#define OST(BUF, R) do {                                                 \
    short* As_ = smem_o + (BUF) * 5120;                                  \
    short* Bt_ = As_ + 2560;                                             \
    *(bf16x8*)&As_[ar * 40 + akc] = R[0];                                \
    *(bf16x8*)&Bt_[ar * 40 + akc] = R[1];                                \
  } while (0)
#define OMM(BUF) do {                                                    \
    const short* As_ = smem_o + (BUF) * 5120;                            \
    const short* Bt_ = As_ + 2560;                                       \
    bf16x8 aA[2], bB[2];                                                 \
    for (int mi = 0; mi < 2; ++mi)                                       \
      aA[mi] = *(const bf16x8*)&As_[(wm * 32 + mi * 16 + l15) * 40 + quad * 8]; \
    for (int ni = 0; ni < 2; ++ni)                                       \
      bB[ni] = *(const bf16x8*)&Bt_[(wn * 32 + ni * 16 + l15) * 40 + quad * 8]; \
    for (int mi = 0; mi < 2; ++mi)                                       \
      for (int ni = 0; ni < 2; ++ni)                                     \
        acc[mi][ni] = __builtin_amdgcn_mfma_f32_16x16x32_bf16(           \
            aA[mi], bB[ni], acc[mi][ni], 0, 0, 0);                       \
  } while (0)

  bf16x8 rA[2], rB[2];
  OLD(rA, 0); OST(0, rA);
  OLD(rA, 32);
  __syncthreads();
#pragma unroll 1
  for (int k0 = 0; k0 < 512; k0 += 64) {
    if (k0 + 64 < 512) OLD(rB, k0 + 64);
    OMM(0);
    OST(1, rA);
    __syncthreads();
    if (k0 + 96 < 512) OLD(rA, k0 + 96);
    OMM(1);
    if (k0 + 64 < 512) { OST(0, rB); __syncthreads(); }
  }
#undef OLD
#undef OST
#undef OMM

#pragma unroll
  for (int mi = 0; mi < 2; ++mi)
#pragma unroll
    for (int ni = 0; ni < 2; ++ni)
#pragma unroll
      for (int r = 0; r < 4; ++r) {
        int row = m0 + wm * 32 + mi * 16 + quad * 4 + r;
        int col = n0 + wn * 32 + ni * 16 + l15;
        Co[(size_t)row * 512 + col] = acc[mi][ni][r] + bias[col];
      }
}

// =====================================================================
extern "C" void kernel_launch(void* const* d_in, const int* in_sizes, int n_in,
                              void* d_out, int out_size, void* d_ws, size_t ws_size,
                              hipStream_t stream)
{
  const float* x     = (const float*)d_in[0];
  const float* w_qkv = (const float*)d_in[1];
  const float* b_qkv = (const float*)d_in[2];
  const float* w_od  = (const float*)d_in[3];
  const float* b_od  = (const float*)d_in[4];
  const float* w_out = (const float*)d_in[5];
  const float* b_out = (const float*)d_in[6];
  float* out = (float*)d_out;

  char* w = (char*)d_ws;
  short* xb    = (short*)w;  w += (size_t)B * T * E * 2;           // 4 MB
  short* wTq   = (short*)w;  w += (size_t)E * 3 * E * 2;           // 1.5 MB
  short* wTo   = (short*)w;  w += (size_t)E * E * 2;               // 0.5 MB
  short* qkvb  = (short*)w;  w += (size_t)B * T * 3 * E * 2;       // 12.6 MB
  short* Vtg   = (short*)w;  w += (size_t)B * T * E * 2;           // 4 MB
  float* Wc    = (float*)w;  w += (size_t)E * 16 * 4;              // 32 KB
  float* bc    = (float*)w;  w += 256;
  float* prm   = (float*)w;  w += (size_t)7 * NT * 4;              // 896 KB
  short* Opart = (short*)w;  w += (size_t)KSPLIT * B * T * E * 2;  // 16.8 MB
  float* lpart = (float*)w;  w += (size_t)KSPLIT * NT * 4;         // 512 KB
  short* attnb = (short*)w;  w += (size_t)B * T * E * 2;           // 4 MB

  // 1) fused prep: casts + transposes + combined od weights
  prep_all<<<dim3(3105), 256, 0, stream>>>(
      x, w_qkv, b_qkv, w_od, b_od, xb, wTq, wTo, w_out, Wc, bc);

  // 2) fused qkv GEMM (V transposed, Q pre-scaled) + od/window params
  qkv_od<<<dim3(1024), 256, 0, stream>>>(
      xb, wTq, b_qkv, qkvb, Vtg, x, Wc, bc, prm);

  // 3) attention (2-deep prefetch dbuf flash, K-split 4-way)
  flash_attn_mfma6<<<dim3(T / 64, BH, KSPLIT), 256, 0, stream>>>(
      qkvb, Vtg, prm, Opart, lpart);

  // 4) combine partials -> attn bf16
  combine_attn<<<dim3(B * T * E / 2048), 256, 0, stream>>>(Opart, lpart, attnb);

  // 5) out = attn @ w_out + b_out
  out_gemm_bf16<<<dim3(E / 64, B * T / 64), 256, 0, stream>>>(
      attnb, wTo, b_out, out);
}

// Round 9
// 181.013 us; speedup vs baseline: 1.1216x; 1.1216x over previous
//
#include <hip/hip_runtime.h>
#include <math.h>

typedef float vf4 __attribute__((ext_vector_type(4)));
typedef float f32x4 __attribute__((ext_vector_type(4)));
typedef short bf16x8 __attribute__((ext_vector_type(8)));
typedef short short4v __attribute__((ext_vector_type(4)));
typedef int int2v __attribute__((ext_vector_type(2)));
typedef int int4v __attribute__((ext_vector_type(4)));

constexpr int B = 2, T = 2048, E = 512, NH = 8, HD = 64;
constexpr int BH = B * NH;            // 16
constexpr int NT = BH * T;            // 32768
constexpr int KSPLIT = 4;
constexpr float SCALE = 0.125f;       // HD^-0.5
constexpr float LOG2E = 1.44269504088896f;
constexpr float QSC = SCALE * LOG2E;  // folded into Q -> S in log2 domain

static __device__ __forceinline__ short f2bf(float f) {
  unsigned u = __float_as_uint(f);
  unsigned r = (u + 0x7fffu + ((u >> 16) & 1u)) >> 16;   // RNE
  return (short)r;
}
static __device__ __forceinline__ unsigned pk2bf(float a, float b) {  // RNE pack
  unsigned lo = (unsigned)(unsigned short)f2bf(a);
  unsigned hi = (unsigned)(unsigned short)f2bf(b);
  return lo | (hi << 16);
}
// cheap half-up bf16 pack (unbiased, <=2^-9 rel err) — inner-loop use
static __device__ __forceinline__ unsigned pkhu(float a, float b) {
  unsigned ua = __float_as_uint(a) + 0x8000u;
  unsigned ub = __float_as_uint(b) + 0x8000u;
  return __builtin_amdgcn_perm(ub, ua, 0x07060302u);  // [ua.hi16 | ub.hi16]
}
#if __has_builtin(__builtin_amdgcn_exp2f)
#define EXP2F(x) __builtin_amdgcn_exp2f(x)
#else
#define EXP2F(x) exp2f(x)
#endif
static __device__ __forceinline__ float bf2f(short s) {
  return __uint_as_float(((unsigned)(unsigned short)s) << 16);
}

// =====================================================================
// prep_all: fused cast_x | w_qkv^T | w_out^T | w_comb.  Grid 3105 blocks.
// =====================================================================
__global__ __launch_bounds__(256) void prep_all(
    const float* __restrict__ x, const float* __restrict__ w_qkv,
    const float* __restrict__ b_qkv, const float* __restrict__ w_od,
    const float* __restrict__ b_od,
    short* __restrict__ xb, short* __restrict__ wTq, short* __restrict__ wTo,
    const float* __restrict__ w_out, float* __restrict__ Wc,
    float* __restrict__ bc)
{
  __shared__ float sh[8464];
  const int bid = blockIdx.x;
  const int tid = threadIdx.x;

  if (bid < 2048) {                       // ---- cast x -> bf16
    int idx = (bid * 256 + tid) * 4;
    vf4 v = *(const vf4*)&x[idx];
    short4v o;
    o[0] = f2bf(v[0]); o[1] = f2bf(v[1]); o[2] = f2bf(v[2]); o[3] = f2bf(v[3]);
    *(short4v*)&xb[idx] = o;
  } else if (bid < 3072) {                // ---- transpose-cast weights
    const float* w; short* wT; int N, t;
    if (bid < 2816) { t = bid - 2048; w = w_qkv; wT = wTq; N = 1536; }
    else            { t = bid - 2816; w = w_out; wT = wTo; N = 512; }
    float (*tt)[33] = (float(*)[33])sh;
    const int k0 = (t & 15) * 32;
    const int n0 = (t >> 4) * 32;
    const int c = tid & 31, r = tid >> 5;  // r: 0..7
#pragma unroll
    for (int p = 0; p < 4; ++p)
      tt[r + p * 8][c] = w[(size_t)(k0 + r + p * 8) * N + n0 + c];
    __syncthreads();
#pragma unroll
    for (int p = 0; p < 4; ++p)
      wT[(size_t)(n0 + r + p * 8) * 512 + k0 + c] = f2bf(tt[c][r + p * 8]);
  } else {                                // ---- w_comb
    float* Lod = sh;                 // 512*16
    float (*pb)[17] = (float(*)[17])(sh + 8192);
    const int bx = bid - 3072;       // 0..32
#pragma unroll
    for (int p = 0; p < 8; ++p) {
      int idx = (p * 256 + tid) * 4;
      *(vf4*)&Lod[idx] = *(const vf4*)&w_od[idx];
    }
    __syncthreads();
    if (bx < 32) {
      const int k = bx * 16 + (tid >> 4);
      const int c = tid & 15;
      float s = 0.0f;
      for (int m = 0; m < E; m += 4) {
        vf4 wq = *(const vf4*)&w_qkv[(size_t)k * 1536 + m];
        s += wq[0] * Lod[(m + 0) * 16 + c] + wq[1] * Lod[(m + 1) * 16 + c]
           + wq[2] * Lod[(m + 2) * 16 + c] + wq[3] * Lod[(m + 3) * 16 + c];
      }
      Wc[k * 16 + c] = s;
    } else {
      const int c = tid & 15, seg = tid >> 4;
      float s = 0.0f;
      for (int m = seg * 32; m < seg * 32 + 32; ++m)
        s += b_qkv[m] * Lod[m * 16 + c];
      pb[seg][c] = s;
      __syncthreads();
      if (tid < 16) {
        float acc = b_od[tid];
#pragma unroll
        for (int g = 0; g < 16; ++g) acc += pb[g][tid];
        bc[tid] = acc;
      }
    }
  }
}

// =====================================================================
// Fused qkv GEMM + od/window-params.  Grid 1024: blocks 0..767 GEMM
// (128x64 tiles, BK=32, double-buffered, 1 barrier/iter); 768..1023 od.
// =====================================================================
__global__ __launch_bounds__(256) void qkv_od(
    const short* __restrict__ xb, const short* __restrict__ wT,
    const float* __restrict__ bias, short* __restrict__ qkvb,
    short* __restrict__ Vtg,
    const float* __restrict__ x, const float* __restrict__ Wc,
    const float* __restrict__ bc, float* __restrict__ prm)
{
  __shared__ __align__(16) short smem_s[16896];   // 33792 B
  const int bid = blockIdx.x;
  const int tid = threadIdx.x;

  if (bid < 768) {
    // ---------------- qkv GEMM 128x64, dbuf ----------------
    const int wave = tid >> 6, lane = tid & 63;
    const int quad = lane >> 4, l15 = lane & 15;
    const int wm = wave >> 1, wn = wave & 1;
    const int bx = bid % 24, by = bid / 24;
    const int m0 = by * 128, n0 = bx * 64;

    f32x4 acc[4][2];
#pragma unroll
    for (int mi = 0; mi < 4; ++mi)
#pragma unroll
      for (int ni = 0; ni < 2; ++ni) acc[mi][ni] = (f32x4){0, 0, 0, 0};

    const int sr = tid >> 1, sc = (tid & 1) * 16;     // A: 128 x 32
    const int br2 = tid >> 2, bk2 = (tid & 3) * 8;    // B: 64 x 32

#define QLD(R, K0) do {                                                   \
      R[0] = *(const bf16x8*)&xb[(size_t)(m0 + sr) * 512 + (K0) + sc];    \
      R[1] = *(const bf16x8*)&xb[(size_t)(m0 + sr) * 512 + (K0) + sc + 8];\
      R[2] = *(const bf16x8*)&wT[(size_t)(n0 + br2) * 512 + (K0) + bk2];  \
    } while (0)
#define QST(BUF, R) do {                                                  \
      short* As_ = smem_s + (BUF) * 7680;                                 \
      short* Bt_ = As_ + 5120;                                            \
      *(bf16x8*)&As_[sr * 40 + sc] = R[0];                                \
      *(bf16x8*)&As_[sr * 40 + sc + 8] = R[1];                            \
      *(bf16x8*)&Bt_[br2 * 40 + bk2] = R[2];                              \
    } while (0)
#define QMM(BUF) do {                                                     \
      const short* As_ = smem_s + (BUF) * 7680;                           \
      const short* Bt_ = As_ + 5120;                                      \
      bf16x8 aA[4], bB[2];                                                \
      for (int mi = 0; mi < 4; ++mi)                                      \
        aA[mi] = *(const bf16x8*)&As_[(wm * 64 + mi * 16 + l15) * 40 + quad * 8]; \
      for (int ni = 0; ni < 2; ++ni)                                      \
        bB[ni] = *(const bf16x8*)&Bt_[(wn * 32 + ni * 16 + l15) * 40 + quad * 8]; \
      for (int mi = 0; mi < 4; ++mi)                                      \
        for (int ni = 0; ni < 2; ++ni)                                    \
          acc[mi][ni] = __builtin_amdgcn_mfma_f32_16x16x32_bf16(          \
              aA[mi], bB[ni], acc[mi][ni], 0, 0, 0);                      \
    } while (0)

    bf16x8 rA[3], rB[3];
    QLD(rA, 0); QST(0, rA);
    QLD(rA, 32);
    __syncthreads();
#pragma unroll 1
    for (int k0 = 0; k0 < 512; k0 += 64) {
      if (k0 + 64 < 512) QLD(rB, k0 + 64);
      QMM(0);
      QST(1, rA);
      __syncthreads();
      if (k0 + 96 < 512) QLD(rA, k0 + 96);
      QMM(1);
      if (k0 + 64 < 512) { QST(0, rB); __syncthreads(); }
    }
#undef QLD
#undef QST
#undef QMM

#pragma unroll
    for (int mi = 0; mi < 4; ++mi)
#pragma unroll
      for (int ni = 0; ni < 2; ++ni) {
        const int col = n0 + wn * 32 + ni * 16 + l15;
        const int rowb = m0 + wm * 64 + mi * 16 + quad * 4;
        const float bs = bias[col];
        if (col < 1024) {
          const float qs = (col < 512) ? QSC : 1.0f;
#pragma unroll
          for (int r = 0; r < 4; ++r)
            qkvb[(size_t)(rowb + r) * 1536 + col] =
                f2bf((acc[mi][ni][r] + bs) * qs);
        } else {
          // V: transposed write  Vtg[(b*8+h)*64+hd][t]
          const int h = (col - 1024) >> 6, hd = col & 63;
          const int b = rowb >> 11, tt = rowb & 2047;
          int2v pk;
          pk[0] = (int)pk2bf(acc[mi][ni][0] + bs, acc[mi][ni][1] + bs);
          pk[1] = (int)pk2bf(acc[mi][ni][2] + bs, acc[mi][ni][3] + bs);
          *(int2v*)&Vtg[(size_t)(((b << 3) + h) * 64 + hd) * T + tt] = pk;
        }
      }
  } else {
    // ---------------- od + window params (fp32 exact) ----------------
    float* Lod = (float*)smem_s;            // 8192 floats (Wc staged)
    float* ods = ((float*)smem_s) + 8192;   // 16x16
    const int obx = bid - 768;
#pragma unroll
    for (int p = 0; p < 8; ++p) {
      int idx = (p * 256 + tid) * 4;
      *(vf4*)&Lod[idx] = *(const vf4*)&Wc[idx];
    }
    __syncthreads();

    const int r = tid >> 4, c = tid & 15;
    const int row = obx * 16 + r;
    float sum = bc[c];
    const float* qr = x + (size_t)row * E;
    for (int k = 0; k < E; k += 4) {
      vf4 q = *(const vf4*)&qr[k];
      sum += q[0] * Lod[(k + 0) * 16 + c]
           + q[1] * Lod[(k + 1) * 16 + c]
           + q[2] * Lod[(k + 2) * 16 + c]
           + q[3] * Lod[(k + 3) * 16 + c];
    }
    ods[r * 16 + c] = sum;
    __syncthreads();

    if (tid < 128) {
      const int rr = tid >> 3, h = tid & 7;
      const int grow = obx * 16 + rr;
      const int b = grow / T, i = grow % T;
      float o = ods[rr * 16 + h];
      float d = ods[rr * 16 + h + 8];
      float offset   = tanhf(o) * (float)T;
      float duration = (float)T / (1.0f + expf(-d));
      float anchor = (float)i + offset;
      float start = anchor - duration;
      float end   = anchor + duration;
      float bl = floorf(start);
      float br = ceilf(end);
      float al = floorf(anchor);
      float wbl = bl - start;
      float wbr = end - br;
      float af  = anchor - al;
      float rsc = 1.0f;
      if (br < 0.0f || bl > (float)(T - 1)) {
        bl = 0.0f; br = (float)(T - 1);
        wbl = 0.0f; wbr = 0.0f; al = -5.0f; af = 0.0f;
        rsc = 0.0f;
      }
      int idx = (b * NH + h) * T + i;
      prm[0 * NT + idx] = bl;
      prm[1 * NT + idx] = br;
      prm[2 * NT + idx] = wbl;
      prm[3 * NT + idx] = wbr;
      prm[4 * NT + idx] = al;
      prm[5 * NT + idx] = af;
      prm[6 * NT + idx] = rsc;
    }
  }
}

// =====================================================================
// MFMA flash attention (round-7 proven pipeline): transposed-S,
// log2-domain, K-split 4-way, LDS dbuf w/ 1-deep register prefetch,
// ONE barrier/tile. l summed by ones-fragment MFMA. Opart bf16.
// =====================================================================
__global__ __launch_bounds__(256, 4) void flash_attn_mfma7(
    const short* __restrict__ qkvb, const short* __restrict__ Vtg,
    const float* __restrict__ prm,
    short* __restrict__ Opart, float* __restrict__ lpart)
{
  __shared__ __align__(16) short Ks[2][64 * 72];
  __shared__ __align__(16) short Vt[2][64 * 72];
  __shared__ __align__(16) short Ps[4][16 * 72];
  __shared__ float u_s[8];

  const int tid = threadIdx.x;
  const int wave = tid >> 6, lane = tid & 63;
  const int quad = lane >> 4, l15 = lane & 15;
  const int qt = blockIdx.x, bh = blockIdx.y, ks = blockIdx.z;
  const int b = bh >> 3, h = bh & 7;
  const int i0 = qt * 64;
  const int i = i0 + wave * 16 + l15;          // this lane's query row

  const int pidx = bh * T + i;
  float blf = prm[0 * NT + pidx];
  float brf = prm[1 * NT + pidx];
  float wbl = prm[2 * NT + pidx];
  float wbr = prm[3 * NT + pidx];
  float alf = prm[4 * NT + pidx];
  float afr = prm[5 * NT + pidx];
  float rsc = prm[6 * NT + pidx];
  const int bli = (int)blf, widi = (int)brf - bli, ali = (int)alf;
  const unsigned widu = (unsigned)widi;
  const float a1 = 1.0f - afr;

  // Q fragment (B-frag: lane = i, regs = hd); zeroed for degenerate rows
  bf16x8 aQ0, aQ1;
  {
    size_t bq = (size_t)(b * T + i) * 1536 + h * 64;
    aQ0 = *(const bf16x8*)&qkvb[bq + quad * 8];
    aQ1 = *(const bf16x8*)&qkvb[bq + 32 + quad * 8];
    if (rsc == 0.0f) {
      bf16x8 z = {0, 0, 0, 0, 0, 0, 0, 0};
      aQ0 = z; aQ1 = z;
    }
  }

  // block union of windows -> K-tile range for this split
  float bmn = blf, bmx = brf;
#pragma unroll
  for (int d = 1; d < 64; d <<= 1) {
    bmn = fminf(bmn, __shfl_xor(bmn, d));
    bmx = fmaxf(bmx, __shfl_xor(bmx, d));
  }
  if (lane == 0) { u_s[wave * 2] = bmn; u_s[wave * 2 + 1] = bmx; }
  __syncthreads();
  bmn = fminf(fminf(u_s[0], u_s[2]), fminf(u_s[4], u_s[6]));
  bmx = fmaxf(fmaxf(u_s[1], u_s[3]), fmaxf(u_s[5], u_s[7]));
  const int ktlo = max(ks * 8, max(((int)bmn) >> 6, 0));
  const int kthi = min(ks * 8 + 7, min(((int)bmx) >> 6, T / 64 - 1));

  f32x4 o[4];
#pragma unroll
  for (int c = 0; c < 4; ++c) o[c] = (f32x4){0, 0, 0, 0};
  f32x4 lq = (f32x4){0, 0, 0, 0};
  const short BF1 = (short)0x3F80;
  const bf16x8 vone = {BF1, BF1, BF1, BF1, BF1, BF1, BF1, BF1};

  const int rq = tid >> 3, cb = (tid & 7) * 8;
  const short* kbase = qkvb + (size_t)b * T * 1536 + 512 + h * 64 + cb;
  const short* vbase = Vtg + (size_t)bh * 64 * T + cb;

  // preload first tile
  bf16x8 kr0, kr1, vr0, vr1;
  if (ktlo <= kthi) {
    const int j0 = ktlo * 64;
    kr0 = *(const bf16x8*)&kbase[(size_t)(j0 + rq) * 1536];
    kr1 = *(const bf16x8*)&kbase[(size_t)(j0 + 32 + rq) * 1536];
    vr0 = *(const bf16x8*)&vbase[(size_t)rq * T + j0];
    vr1 = *(const bf16x8*)&vbase[(size_t)(32 + rq) * T + j0];
    *(bf16x8*)&Ks[0][rq * 72 + cb] = kr0;
    *(bf16x8*)&Ks[0][(32 + rq) * 72 + cb] = kr1;
    *(bf16x8*)&Vt[0][rq * 72 + cb] = vr0;
    *(bf16x8*)&Vt[0][(32 + rq) * 72 + cb] = vr1;
  }
  __syncthreads();

  int buf = 0;
#pragma unroll 1
  for (int kt = ktlo; kt <= kthi; ++kt) {
    const int j0 = kt * 64;
    // prefetch next tile into registers (overlaps with compute below)
    if (kt < kthi) {
      const int j1 = j0 + 64;
      kr0 = *(const bf16x8*)&kbase[(size_t)(j1 + rq) * 1536];
      kr1 = *(const bf16x8*)&kbase[(size_t)(j1 + 32 + rq) * 1536];
      vr0 = *(const bf16x8*)&vbase[(size_t)rq * T + j1];
      vr1 = *(const bf16x8*)&vbase[(size_t)(32 + rq) * T + j1];
    }

    const short* KsB = Ks[buf];
    const short* VtB = Vt[buf];

    // ---- S^T = K Q^T (log2 domain): regs = j, lane = i ----
    f32x4 s[4];
#pragma unroll
    for (int nc = 0; nc < 4; ++nc) {
      const short* kb = &KsB[(nc * 16 + l15) * 72 + quad * 8];
      f32x4 a = (f32x4){0, 0, 0, 0};
      a = __builtin_amdgcn_mfma_f32_16x16x32_bf16(*(const bf16x8*)&kb[0],  aQ0, a, 0, 0, 0);
      a = __builtin_amdgcn_mfma_f32_16x16x32_bf16(*(const bf16x8*)&kb[32], aQ1, a, 0, 0, 0);
      s[nc] = a;
    }

    // interior tile for every row of this wave? (wave-uniform branch)
    const int clean = (bli < j0) & (bli + widi > j0 + 63) &
                      ((ali > j0 + 63) | (ali + 1 < j0));
    if (__all(clean)) {
      // ---- fast path: p = exp2(s) ----
#pragma unroll
      for (int nc = 0; nc < 4; ++nc) {
        float p0 = EXP2F(s[nc][0]);
        float p1 = EXP2F(s[nc][1]);
        float p2 = EXP2F(s[nc][2]);
        float p3 = EXP2F(s[nc][3]);
        int2v pk;
        pk[0] = (int)pkhu(p0, p1);
        pk[1] = (int)pkhu(p2, p3);
        *(int2v*)&Ps[wave][l15 * 72 + nc * 16 + quad * 4] = pk;
      }
    } else {
      // ---- slow path: weights + mask ----
      const int dq  = j0 + quad * 4 - bli;
      const int dq2 = j0 + quad * 4 - ali;
#pragma unroll
      for (int nc = 0; nc < 4; ++nc) {
        const int dn = dq + nc * 16, d2n = dq2 + nc * 16;
        float pr[4];
#pragma unroll
        for (int r = 0; r < 4; ++r) {
          int d = dn + r, d2 = d2n + r;
          float e  = (d == 0) ? wbl : ((d == widi) ? wbr : 0.0f);
          float aw = (d2 == 0) ? a1 : ((d2 == 1) ? afr : 0.0f);
          float w = 1.0f + e + aw;
          float v = s[nc][r] * w;                    // log2 domain
          v = ((unsigned)d <= widu) ? v : -115.0f;
          pr[r] = EXP2F(v);
        }
        int2v pk;
        pk[0] = (int)pkhu(pr[0], pr[1]);
        pk[1] = (int)pkhu(pr[2], pr[3]);
        *(int2v*)&Ps[wave][l15 * 72 + nc * 16 + quad * 4] = pk;
      }
    }
    // wave-private Ps: no barrier needed

    // ---- O^T += V^T P^T ; l += ones^T P^T ----
    bf16x8 bP0 = *(const bf16x8*)&Ps[wave][l15 * 72 + quad * 8];
    bf16x8 bP1 = *(const bf16x8*)&Ps[wave][l15 * 72 + 32 + quad * 8];
    lq = __builtin_amdgcn_mfma_f32_16x16x32_bf16(vone, bP0, lq, 0, 0, 0);
    lq = __builtin_amdgcn_mfma_f32_16x16x32_bf16(vone, bP1, lq, 0, 0, 0);
#pragma unroll
    for (int nc2 = 0; nc2 < 4; ++nc2) {
      const short* vb = &VtB[(nc2 * 16 + l15) * 72 + quad * 8];
      o[nc2] = __builtin_amdgcn_mfma_f32_16x16x32_bf16(
          *(const bf16x8*)&vb[0],  bP0, o[nc2], 0, 0, 0);
      o[nc2] = __builtin_amdgcn_mfma_f32_16x16x32_bf16(
          *(const bf16x8*)&vb[32], bP1, o[nc2], 0, 0, 0);
    }

    // ---- write prefetched tile to alternate buffer; ONE barrier ----
    if (kt < kthi) {
      short* Kn = Ks[buf ^ 1];
      short* Vn = Vt[buf ^ 1];
      *(bf16x8*)&Kn[rq * 72 + cb] = kr0;
      *(bf16x8*)&Kn[(32 + rq) * 72 + cb] = kr1;
      *(bf16x8*)&Vn[rq * 72 + cb] = vr0;
      *(bf16x8*)&Vn[(32 + rq) * 72 + cb] = vr1;
      __syncthreads();
      buf ^= 1;
    }
  }

  // l: every lane's lq[0] holds the full row-sum for its i (ones-MFMA)
  if (lane < 16)
    lpart[ks * NT + bh * T + i] = lq[0];

  // O^T epilogue (bf16): lane = row i, regs = channels c
  size_t ob = (size_t)ks * (B * T * E) + (size_t)(b * T + i) * E + h * 64;
#pragma unroll
  for (int nc2 = 0; nc2 < 4; ++nc2) {
    int2v pk;
    pk[0] = (int)pk2bf(o[nc2][0], o[nc2][1]);
    pk[1] = (int)pk2bf(o[nc2][2], o[nc2][3]);
    *(int2v*)&Opart[ob + nc2 * 16 + quad * 4] = pk;
  }
}

// =====================================================================
// out GEMM + fused combine: A[m][k] = (sum_s Opart_s[m][k]) / l[m][head],
// normalized+packed during A-staging (numerically identical to the old
// combine->attnb path). out = A @ w_out + b_out (fp32).
// Tile 64x64, BK=32, dbuf (1 barrier/iter). Grid (8, 64) = 512 blocks.
// =====================================================================
__global__ __launch_bounds__(256) void out_gemm_fused(
    const short* __restrict__ Opart, const float* __restrict__ lpart,
    const short* __restrict__ wT, const float* __restrict__ bias,
    float* __restrict__ Co)
{
  __shared__ __align__(16) short smem_o[10240];   // 2 bufs x (64*40 + 64*40)
  __shared__ float inv_s[64 * 8];                 // [row][head]

  const int tid = threadIdx.x;
  const int wave = tid >> 6, lane = tid & 63;
  const int quad = lane >> 4, l15 = lane & 15;
  const int wm = wave >> 1, wn = wave & 1;
  const int m0 = blockIdx.y * 64, n0 = blockIdx.x * 64;

  // precompute 1/l for this block's 64 rows x 8 heads
#pragma unroll
  for (int p = 0; p < 2; ++p) {
    int e = p * 256 + tid;          // 0..511
    int row = e >> 3, hh = e & 7;
    int grow = m0 + row;
    int bb = grow >> 11, ii = grow & (T - 1);
    int lidx = ((bb << 3) + hh) * T + ii;
    float l = (lpart[lidx] + lpart[NT + lidx]) +
              (lpart[2 * NT + lidx] + lpart[3 * NT + lidx]);
    inv_s[e] = 1.0f / l;
  }
  __syncthreads();

  f32x4 acc[2][2];
#pragma unroll
  for (int mi = 0; mi < 2; ++mi)
#pragma unroll
    for (int ni = 0; ni < 2; ++ni) acc[mi][ni] = (f32x4){0, 0, 0, 0};

  const int ar = tid >> 2, akc = (tid & 3) * 8;
  constexpr size_t SLAB = (size_t)B * T * E;

#define OLD(R, K0) do {                                                  \
    size_t abase = (size_t)(m0 + ar) * 512 + (K0) + akc;                 \
    bf16x8 q0 = *(const bf16x8*)&Opart[abase];                           \
    bf16x8 q1 = *(const bf16x8*)&Opart[SLAB + abase];                    \
    bf16x8 q2 = *(const bf16x8*)&Opart[2 * SLAB + abase];                \
    bf16x8 q3 = *(const bf16x8*)&Opart[3 * SLAB + abase];                \
    float iv = inv_s[ar * 8 + (((K0) + akc) >> 6)];                      \
    float fa[8];                                                         \
    for (int j = 0; j < 8; ++j)                                          \
      fa[j] = ((bf2f(q0[j]) + bf2f(q1[j])) +                             \
               (bf2f(q2[j]) + bf2f(q3[j]))) * iv;                        \
    int4v pk_;                                                           \
    pk_[0] = (int)pk2bf(fa[0], fa[1]);                                   \
    pk_[1] = (int)pk2bf(fa[2], fa[3]);                                   \
    pk_[2] = (int)pk2bf(fa[4], fa[5]);                                   \
    pk_[3] = (int)pk2bf(fa[6], fa[7]);                                   \
    R0 = pk_;                                                            \
    R1 = *(const bf16x8*)&wT[(size_t)(n0 + ar) * 512 + (K0) + akc];      \
  } while (0)
#define OST(BUF) do {                                                    \
    short* As_ = smem_o + (BUF) * 5120;                                  \
    short* Bt_ = As_ + 2560;                                             \
    *(int4v*)&As_[ar * 40 + akc] = R0;                                   \
    *(bf16x8*)&Bt_[ar * 40 + akc] = R1;                                  \
  } while (0)
#define OMM(BUF) do {                                                    \
    const short* As_ = smem_o + (BUF) * 5120;                            \
    const short* Bt_ = As_ + 2560;                                       \
    bf16x8 aA[2], bB[2];                                                 \
    for (int mi = 0; mi < 2; ++mi)                                       \
      aA[mi] = *(const bf16x8*)&As_[(wm * 32 + mi * 16 + l15) * 40 + quad * 8]; \
    for (int ni = 0; ni < 2; ++ni)                                       \
      bB[ni] = *(const bf16x8*)&Bt_[(wn * 32 + ni * 16 + l15) * 40 + quad * 8]; \
    for (int mi = 0; mi < 2; ++mi)                                       \
      for (int ni = 0; ni < 2; ++ni)                                     \
        acc[mi][ni] = __builtin_amdgcn_mfma_f32_16x16x32_bf16(           \
            aA[mi], bB[ni], acc[mi][ni], 0, 0, 0);                       \
  } while (0)

  int4v R0; bf16x8 R1;
  OLD(, 0); OST(0);
  OLD(, 32);
  __syncthreads();
#pragma unroll 1
  for (int k0 = 0; k0 < 512; k0 += 64) {
    OMM(0);
    OST(1);
    __syncthreads();
    if (k0 + 64 < 512) OLD(, k0 + 64);
    OMM(1);
    if (k0 + 64 < 512) {
      OST(0);
      __syncthreads();
      if (k0 + 96 < 512) OLD(, k0 + 96);
    }
  }
#undef OLD
#undef OST
#undef OMM

#pragma unroll
  for (int mi = 0; mi < 2; ++mi)
#pragma unroll
    for (int ni = 0; ni < 2; ++ni)
#pragma unroll
      for (int r = 0; r < 4; ++r) {
        int row = m0 + wm * 32 + mi * 16 + quad * 4 + r;
        int col = n0 + wn * 32 + ni * 16 + l15;
        Co[(size_t)row * 512 + col] = acc[mi][ni][r] + bias[col];
      }
}

// =====================================================================
extern "C" void kernel_launch(void* const* d_in, const int* in_sizes, int n_in,
                              void* d_out, int out_size, void* d_ws, size_t ws_size,
                              hipStream_t stream)
{
  const float* x     = (const float*)d_in[0];
  const float* w_qkv = (const float*)d_in[1];
  const float* b_qkv = (const float*)d_in[2];
  const float* w_od  = (const float*)d_in[3];
  const float* b_od  = (const float*)d_in[4];
  const float* w_out = (const float*)d_in[5];
  const float* b_out = (const float*)d_in[6];
  float* out = (float*)d_out;

  char* w = (char*)d_ws;
  short* xb    = (short*)w;  w += (size_t)B * T * E * 2;           // 4 MB
  short* wTq   = (short*)w;  w += (size_t)E * 3 * E * 2;           // 1.5 MB
  short* wTo   = (short*)w;  w += (size_t)E * E * 2;               // 0.5 MB
  short* qkvb  = (short*)w;  w += (size_t)B * T * 3 * E * 2;       // 12.6 MB
  short* Vtg   = (short*)w;  w += (size_t)B * T * E * 2;           // 4 MB
  float* Wc    = (float*)w;  w += (size_t)E * 16 * 4;              // 32 KB
  float* bc    = (float*)w;  w += 256;
  float* prm   = (float*)w;  w += (size_t)7 * NT * 4;              // 896 KB
  short* Opart = (short*)w;  w += (size_t)KSPLIT * B * T * E * 2;  // 16.8 MB
  float* lpart = (float*)w;  w += (size_t)KSPLIT * NT * 4;         // 512 KB

  // 1) fused prep: casts + transposes + combined od weights
  prep_all<<<dim3(3105), 256, 0, stream>>>(
      x, w_qkv, b_qkv, w_od, b_od, xb, wTq, wTo, w_out, Wc, bc);

  // 2) fused qkv GEMM (V transposed, Q pre-scaled) + od/window params
  qkv_od<<<dim3(1024), 256, 0, stream>>>(
      xb, wTq, b_qkv, qkvb, Vtg, x, Wc, bc, prm);

  // 3) attention (r7 pipeline + ones-MFMA l, K-split 4-way)
  flash_attn_mfma7<<<dim3(T / 64, BH, KSPLIT), 256, 0, stream>>>(
      qkvb, Vtg, prm, Opart, lpart);

  // 4) out = combine(Opart)/l @ w_out + b_out  (combine fused into staging)
  out_gemm_fused<<<dim3(E / 64, B * T / 64), 256, 0, stream>>>(
      Opart, lpart, wTo, b_out, out);
}

// Round 10
// 165.201 us; speedup vs baseline: 1.2289x; 1.0957x over previous
//
#include <hip/hip_runtime.h>
#include <math.h>

typedef float vf4 __attribute__((ext_vector_type(4)));
typedef float f32x4 __attribute__((ext_vector_type(4)));
typedef short bf16x8 __attribute__((ext_vector_type(8)));
typedef short short4v __attribute__((ext_vector_type(4)));
typedef int int2v __attribute__((ext_vector_type(2)));
typedef int int4v __attribute__((ext_vector_type(4)));

constexpr int B = 2, T = 2048, E = 512, NH = 8, HD = 64;
constexpr int BH = B * NH;            // 16
constexpr int NT = BH * T;            // 32768
constexpr int KSPLIT = 4;
constexpr float SCALE = 0.125f;       // HD^-0.5
constexpr float LOG2E = 1.44269504088896f;
constexpr float QSC = SCALE * LOG2E;  // folded into Q -> S in log2 domain

static __device__ __forceinline__ short f2bf(float f) {
  unsigned u = __float_as_uint(f);
  unsigned r = (u + 0x7fffu + ((u >> 16) & 1u)) >> 16;   // RNE
  return (short)r;
}
static __device__ __forceinline__ unsigned pk2bf(float a, float b) {  // RNE pack
  unsigned lo = (unsigned)(unsigned short)f2bf(a);
  unsigned hi = (unsigned)(unsigned short)f2bf(b);
  return lo | (hi << 16);
}
// cheap half-up bf16 pack (unbiased, <=2^-9 rel err) — inner-loop use
static __device__ __forceinline__ unsigned pkhu(float a, float b) {
  unsigned ua = __float_as_uint(a) + 0x8000u;
  unsigned ub = __float_as_uint(b) + 0x8000u;
  return __builtin_amdgcn_perm(ub, ua, 0x07060302u);  // [ua.hi16 | ub.hi16]
}
#if __has_builtin(__builtin_amdgcn_exp2f)
#define EXP2F(x) __builtin_amdgcn_exp2f(x)
#else
#define EXP2F(x) exp2f(x)
#endif
static __device__ __forceinline__ float bf2f(short s) {
  return __uint_as_float(((unsigned)(unsigned short)s) << 16);
}

// =====================================================================
// prep_all: fused cast_x | w_qkv^T | w_out^T | w_comb.  Grid 3105 blocks.
// =====================================================================
__global__ __launch_bounds__(256) void prep_all(
    const float* __restrict__ x, const float* __restrict__ w_qkv,
    const float* __restrict__ b_qkv, const float* __restrict__ w_od,
    const float* __restrict__ b_od,
    short* __restrict__ xb, short* __restrict__ wTq, short* __restrict__ wTo,
    const float* __restrict__ w_out, float* __restrict__ Wc,
    float* __restrict__ bc)
{
  __shared__ float sh[8464];
  const int bid = blockIdx.x;
  const int tid = threadIdx.x;

  if (bid < 2048) {                       // ---- cast x -> bf16
    int idx = (bid * 256 + tid) * 4;
    vf4 v = *(const vf4*)&x[idx];
    short4v o;
    o[0] = f2bf(v[0]); o[1] = f2bf(v[1]); o[2] = f2bf(v[2]); o[3] = f2bf(v[3]);
    *(short4v*)&xb[idx] = o;
  } else if (bid < 3072) {                // ---- transpose-cast weights
    const float* w; short* wT; int N, t;
    if (bid < 2816) { t = bid - 2048; w = w_qkv; wT = wTq; N = 1536; }
    else            { t = bid - 2816; w = w_out; wT = wTo; N = 512; }
    float (*tt)[33] = (float(*)[33])sh;
    const int k0 = (t & 15) * 32;
    const int n0 = (t >> 4) * 32;
    const int c = tid & 31, r = tid >> 5;  // r: 0..7
#pragma unroll
    for (int p = 0; p < 4; ++p)
      tt[r + p * 8][c] = w[(size_t)(k0 + r + p * 8) * N + n0 + c];
    __syncthreads();
#pragma unroll
    for (int p = 0; p < 4; ++p)
      wT[(size_t)(n0 + r + p * 8) * 512 + k0 + c] = f2bf(tt[c][r + p * 8]);
  } else {                                // ---- w_comb
    float* Lod = sh;                 // 512*16
    float (*pb)[17] = (float(*)[17])(sh + 8192);
    const int bx = bid - 3072;       // 0..32
#pragma unroll
    for (int p = 0; p < 8; ++p) {
      int idx = (p * 256 + tid) * 4;
      *(vf4*)&Lod[idx] = *(const vf4*)&w_od[idx];
    }
    __syncthreads();
    if (bx < 32) {
      const int k = bx * 16 + (tid >> 4);
      const int c = tid & 15;
      float s = 0.0f;
      for (int m = 0; m < E; m += 4) {
        vf4 wq = *(const vf4*)&w_qkv[(size_t)k * 1536 + m];
        s += wq[0] * Lod[(m + 0) * 16 + c] + wq[1] * Lod[(m + 1) * 16 + c]
           + wq[2] * Lod[(m + 2) * 16 + c] + wq[3] * Lod[(m + 3) * 16 + c];
      }
      Wc[k * 16 + c] = s;
    } else {
      const int c = tid & 15, seg = tid >> 4;
      float s = 0.0f;
      for (int m = seg * 32; m < seg * 32 + 32; ++m)
        s += b_qkv[m] * Lod[m * 16 + c];
      pb[seg][c] = s;
      __syncthreads();
      if (tid < 16) {
        float acc = b_od[tid];
#pragma unroll
        for (int g = 0; g < 16; ++g) acc += pb[g][tid];
        bc[tid] = acc;
      }
    }
  }
}

// =====================================================================
// Fused qkv GEMM + od/window-params.  Grid 1024: blocks 0..767 GEMM
// (128x64 tiles, BK=32, double-buffered, 1 barrier/iter); 768..1023 od.
// =====================================================================
__global__ __launch_bounds__(256) void qkv_od(
    const short* __restrict__ xb, const short* __restrict__ wT,
    const float* __restrict__ bias, short* __restrict__ qkvb,
    short* __restrict__ Vtg,
    const float* __restrict__ x, const float* __restrict__ Wc,
    const float* __restrict__ bc, float* __restrict__ prm)
{
  __shared__ __align__(16) short smem_s[16896];   // 33792 B
  const int bid = blockIdx.x;
  const int tid = threadIdx.x;

  if (bid < 768) {
    // ---------------- qkv GEMM 128x64, dbuf ----------------
    const int wave = tid >> 6, lane = tid & 63;
    const int quad = lane >> 4, l15 = lane & 15;
    const int wm = wave >> 1, wn = wave & 1;
    const int bx = bid % 24, by = bid / 24;
    const int m0 = by * 128, n0 = bx * 64;

    f32x4 acc[4][2];
#pragma unroll
    for (int mi = 0; mi < 4; ++mi)
#pragma unroll
      for (int ni = 0; ni < 2; ++ni) acc[mi][ni] = (f32x4){0, 0, 0, 0};

    const int sr = tid >> 1, sc = (tid & 1) * 16;     // A: 128 x 32
    const int br2 = tid >> 2, bk2 = (tid & 3) * 8;    // B: 64 x 32

#define QLD(R, K0) do {                                                   \
      R[0] = *(const bf16x8*)&xb[(size_t)(m0 + sr) * 512 + (K0) + sc];    \
      R[1] = *(const bf16x8*)&xb[(size_t)(m0 + sr) * 512 + (K0) + sc + 8];\
      R[2] = *(const bf16x8*)&wT[(size_t)(n0 + br2) * 512 + (K0) + bk2];  \
    } while (0)
#define QST(BUF, R) do {                                                  \
      short* As_ = smem_s + (BUF) * 7680;                                 \
      short* Bt_ = As_ + 5120;                                            \
      *(bf16x8*)&As_[sr * 40 + sc] = R[0];                                \
      *(bf16x8*)&As_[sr * 40 + sc + 8] = R[1];                            \
      *(bf16x8*)&Bt_[br2 * 40 + bk2] = R[2];                              \
    } while (0)
#define QMM(BUF) do {                                                     \
      const short* As_ = smem_s + (BUF) * 7680;                           \
      const short* Bt_ = As_ + 5120;                                      \
      bf16x8 aA[4], bB[2];                                                \
      for (int mi = 0; mi < 4; ++mi)                                      \
        aA[mi] = *(const bf16x8*)&As_[(wm * 64 + mi * 16 + l15) * 40 + quad * 8]; \
      for (int ni = 0; ni < 2; ++ni)                                      \
        bB[ni] = *(const bf16x8*)&Bt_[(wn * 32 + ni * 16 + l15) * 40 + quad * 8]; \
      for (int mi = 0; mi < 4; ++mi)                                      \
        for (int ni = 0; ni < 2; ++ni)                                    \
          acc[mi][ni] = __builtin_amdgcn_mfma_f32_16x16x32_bf16(          \
              aA[mi], bB[ni], acc[mi][ni], 0, 0, 0);                      \
    } while (0)

    bf16x8 rA[3], rB[3];
    QLD(rA, 0); QST(0, rA);
    QLD(rA, 32);
    __syncthreads();
#pragma unroll 1
    for (int k0 = 0; k0 < 512; k0 += 64) {
      if (k0 + 64 < 512) QLD(rB, k0 + 64);
      QMM(0);
      QST(1, rA);
      __syncthreads();
      if (k0 + 96 < 512) QLD(rA, k0 + 96);
      QMM(1);
      if (k0 + 64 < 512) { QST(0, rB); __syncthreads(); }
    }
#undef QLD
#undef QST
#undef QMM

#pragma unroll
    for (int mi = 0; mi < 4; ++mi)
#pragma unroll
      for (int ni = 0; ni < 2; ++ni) {
        const int col = n0 + wn * 32 + ni * 16 + l15;
        const int rowb = m0 + wm * 64 + mi * 16 + quad * 4;
        const float bs = bias[col];
        if (col < 1024) {
          const float qs = (col < 512) ? QSC : 1.0f;
#pragma unroll
          for (int r = 0; r < 4; ++r)
            qkvb[(size_t)(rowb + r) * 1536 + col] =
                f2bf((acc[mi][ni][r] + bs) * qs);
        } else {
          // V: transposed write  Vtg[(b*8+h)*64+hd][t]
          const int h = (col - 1024) >> 6, hd = col & 63;
          const int b = rowb >> 11, tt = rowb & 2047;
          int2v pk;
          pk[0] = (int)pk2bf(acc[mi][ni][0] + bs, acc[mi][ni][1] + bs);
          pk[1] = (int)pk2bf(acc[mi][ni][2] + bs, acc[mi][ni][3] + bs);
          *(int2v*)&Vtg[(size_t)(((b << 3) + h) * 64 + hd) * T + tt] = pk;
        }
      }
  } else {
    // ---------------- od + window params (fp32 exact) ----------------
    float* Lod = (float*)smem_s;            // 8192 floats (Wc staged)
    float* ods = ((float*)smem_s) + 8192;   // 16x16
    const int obx = bid - 768;
#pragma unroll
    for (int p = 0; p < 8; ++p) {
      int idx = (p * 256 + tid) * 4;
      *(vf4*)&Lod[idx] = *(const vf4*)&Wc[idx];
    }
    __syncthreads();

    const int r = tid >> 4, c = tid & 15;
    const int row = obx * 16 + r;
    float sum = bc[c];
    const float* qr = x + (size_t)row * E;
    for (int k = 0; k < E; k += 4) {
      vf4 q = *(const vf4*)&qr[k];
      sum += q[0] * Lod[(k + 0) * 16 + c]
           + q[1] * Lod[(k + 1) * 16 + c]
           + q[2] * Lod[(k + 2) * 16 + c]
           + q[3] * Lod[(k + 3) * 16 + c];
    }
    ods[r * 16 + c] = sum;
    __syncthreads();

    if (tid < 128) {
      const int rr = tid >> 3, h = tid & 7;
      const int grow = obx * 16 + rr;
      const int b = grow / T, i = grow % T;
      float o = ods[rr * 16 + h];
      float d = ods[rr * 16 + h + 8];
      float offset   = tanhf(o) * (float)T;
      float duration = (float)T / (1.0f + expf(-d));
      float anchor = (float)i + offset;
      float start = anchor - duration;
      float end   = anchor + duration;
      float bl = floorf(start);
      float br = ceilf(end);
      float al = floorf(anchor);
      float wbl = bl - start;
      float wbr = end - br;
      float af  = anchor - al;
      float rsc = 1.0f;
      if (br < 0.0f || bl > (float)(T - 1)) {
        bl = 0.0f; br = (float)(T - 1);
        wbl = 0.0f; wbr = 0.0f; al = -5.0f; af = 0.0f;
        rsc = 0.0f;
      }
      int idx = (b * NH + h) * T + i;
      prm[0 * NT + idx] = bl;
      prm[1 * NT + idx] = br;
      prm[2 * NT + idx] = wbl;
      prm[3 * NT + idx] = wbr;
      prm[4 * NT + idx] = al;
      prm[5 * NT + idx] = af;
      prm[6 * NT + idx] = rsc;
    }
  }
}

// =====================================================================
// MFMA flash attention v8: 128-query block, 2 query-groups per wave.
// Each K/V ds_read_b128 feeds TWO MFMAs (groups a,b) -> per-unit LDS
// traffic ~1.8x lower; K/V global staging amortized over 128 queries.
// r7 proven pipeline: LDS dbuf + 1-deep register prefetch, 1 barrier
// per tile, scalar lacc (ones-MFMA reverted — r8/r9 showed it costs
// 12us via dependent-MFMA serialization). Grid (T/128, BH, KSPLIT).
// =====================================================================
__global__ __launch_bounds__(256, 2) void flash_attn_mfma8(
    const short* __restrict__ qkvb, const short* __restrict__ Vtg,
    const float* __restrict__ prm,
    short* __restrict__ Opart, float* __restrict__ lpart)
{
  __shared__ __align__(16) short Ks[2][64 * 72];
  __shared__ __align__(16) short Vt[2][64 * 72];
  __shared__ __align__(16) short Ps[4][32 * 72];
  __shared__ float u_s[8];

  const int tid = threadIdx.x;
  const int wave = tid >> 6, lane = tid & 63;
  const int quad = lane >> 4, l15 = lane & 15;
  const int qt = blockIdx.x, bh = blockIdx.y, ks = blockIdx.z;
  const int b = bh >> 3, h = bh & 7;
  const int i0 = qt * 128;
  const int ia = i0 + wave * 32 + l15;   // group-a query row
  const int ib = ia + 16;                // group-b query row

  const int pa = bh * T + ia, pb_ = pa + 16;
  float blfA = prm[0 * NT + pa],  brfA = prm[1 * NT + pa];
  float wblA = prm[2 * NT + pa],  wbrA = prm[3 * NT + pa];
  float alfA = prm[4 * NT + pa],  afrA = prm[5 * NT + pa];
  float rscA = prm[6 * NT + pa];
  float blfB = prm[0 * NT + pb_], brfB = prm[1 * NT + pb_];
  float wblB = prm[2 * NT + pb_], wbrB = prm[3 * NT + pb_];
  float alfB = prm[4 * NT + pb_], afrB = prm[5 * NT + pb_];
  float rscB = prm[6 * NT + pb_];
  const int bliA = (int)blfA, widA = (int)brfA - bliA, aliA = (int)alfA;
  const int bliB = (int)blfB, widB = (int)brfB - bliB, aliB = (int)alfB;
  const unsigned widuA = (unsigned)widA, widuB = (unsigned)widB;
  const float a1A = 1.0f - afrA, a1B = 1.0f - afrB;

  // Q fragments (B-frag: lane = i, regs = hd); zeroed for degenerate rows
  bf16x8 aQ0a, aQ1a, aQ0b, aQ1b;
  {
    size_t bqa = (size_t)(b * T + ia) * 1536 + h * 64;
    aQ0a = *(const bf16x8*)&qkvb[bqa + quad * 8];
    aQ1a = *(const bf16x8*)&qkvb[bqa + 32 + quad * 8];
    size_t bqb = bqa + (size_t)16 * 1536;
    aQ0b = *(const bf16x8*)&qkvb[bqb + quad * 8];
    aQ1b = *(const bf16x8*)&qkvb[bqb + 32 + quad * 8];
    bf16x8 z = {0, 0, 0, 0, 0, 0, 0, 0};
    if (rscA == 0.0f) { aQ0a = z; aQ1a = z; }
    if (rscB == 0.0f) { aQ0b = z; aQ1b = z; }
  }

  // block union of windows -> K-tile range for this split
  float bmn = fminf(blfA, blfB), bmx = fmaxf(brfA, brfB);
#pragma unroll
  for (int d = 1; d < 64; d <<= 1) {
    bmn = fminf(bmn, __shfl_xor(bmn, d));
    bmx = fmaxf(bmx, __shfl_xor(bmx, d));
  }
  if (lane == 0) { u_s[wave * 2] = bmn; u_s[wave * 2 + 1] = bmx; }
  __syncthreads();
  bmn = fminf(fminf(u_s[0], u_s[2]), fminf(u_s[4], u_s[6]));
  bmx = fmaxf(fmaxf(u_s[1], u_s[3]), fmaxf(u_s[5], u_s[7]));
  const int ktlo = max(ks * 8, max(((int)bmn) >> 6, 0));
  const int kthi = min(ks * 8 + 7, min(((int)bmx) >> 6, T / 64 - 1));

  f32x4 oA[4], oB[4];
#pragma unroll
  for (int c = 0; c < 4; ++c) { oA[c] = (f32x4){0, 0, 0, 0}; oB[c] = (f32x4){0, 0, 0, 0}; }
  float laccA = 0.0f, laccB = 0.0f;

  const int rq = tid >> 3, cb = (tid & 7) * 8;
  const short* kbase = qkvb + (size_t)b * T * 1536 + 512 + h * 64 + cb;
  const short* vbase = Vtg + (size_t)bh * 64 * T + cb;

  // preload first tile
  bf16x8 kr0, kr1, vr0, vr1;
  if (ktlo <= kthi) {
    const int j0 = ktlo * 64;
    kr0 = *(const bf16x8*)&kbase[(size_t)(j0 + rq) * 1536];
    kr1 = *(const bf16x8*)&kbase[(size_t)(j0 + 32 + rq) * 1536];
    vr0 = *(const bf16x8*)&vbase[(size_t)rq * T + j0];
    vr1 = *(const bf16x8*)&vbase[(size_t)(32 + rq) * T + j0];
    *(bf16x8*)&Ks[0][rq * 72 + cb] = kr0;
    *(bf16x8*)&Ks[0][(32 + rq) * 72 + cb] = kr1;
    *(bf16x8*)&Vt[0][rq * 72 + cb] = vr0;
    *(bf16x8*)&Vt[0][(32 + rq) * 72 + cb] = vr1;
  }
  __syncthreads();

  int buf = 0;
#pragma unroll 1
  for (int kt = ktlo; kt <= kthi; ++kt) {
    const int j0 = kt * 64;
    // prefetch next tile into registers (overlaps with compute below)
    if (kt < kthi) {
      const int j1 = j0 + 64;
      kr0 = *(const bf16x8*)&kbase[(size_t)(j1 + rq) * 1536];
      kr1 = *(const bf16x8*)&kbase[(size_t)(j1 + 32 + rq) * 1536];
      vr0 = *(const bf16x8*)&vbase[(size_t)rq * T + j1];
      vr1 = *(const bf16x8*)&vbase[(size_t)(32 + rq) * T + j1];
    }

    const short* KsB = Ks[buf];
    const short* VtB = Vt[buf];

    // ---- S^T = K Q^T for both groups; each K b128 feeds 2 MFMAs ----
    f32x4 sA[4], sB[4];
#pragma unroll
    for (int nc = 0; nc < 4; ++nc) {
      const short* kb = &KsB[(nc * 16 + l15) * 72 + quad * 8];
      bf16x8 k0 = *(const bf16x8*)&kb[0];
      bf16x8 k1 = *(const bf16x8*)&kb[32];
      f32x4 a = (f32x4){0, 0, 0, 0};
      a = __builtin_amdgcn_mfma_f32_16x16x32_bf16(k0, aQ0a, a, 0, 0, 0);
      a = __builtin_amdgcn_mfma_f32_16x16x32_bf16(k1, aQ1a, a, 0, 0, 0);
      sA[nc] = a;
      f32x4 bq = (f32x4){0, 0, 0, 0};
      bq = __builtin_amdgcn_mfma_f32_16x16x32_bf16(k0, aQ0b, bq, 0, 0, 0);
      bq = __builtin_amdgcn_mfma_f32_16x16x32_bf16(k1, aQ1b, bq, 0, 0, 0);
      sB[nc] = bq;
    }

    // interior tile for every row of this wave? (wave-uniform branch)
    const int cleanA = (bliA < j0) & (bliA + widA > j0 + 63) &
                       ((aliA > j0 + 63) | (aliA + 1 < j0));
    const int cleanB = (bliB < j0) & (bliB + widB > j0 + 63) &
                       ((aliB > j0 + 63) | (aliB + 1 < j0));
    if (__all(cleanA & cleanB)) {
      // ---- fast path: p = exp2(s) ----
#pragma unroll
      for (int nc = 0; nc < 4; ++nc) {
        float p0 = EXP2F(sA[nc][0]);
        float p1 = EXP2F(sA[nc][1]);
        float p2 = EXP2F(sA[nc][2]);
        float p3 = EXP2F(sA[nc][3]);
        laccA += (p0 + p1) + (p2 + p3);
        int2v pk;
        pk[0] = (int)pkhu(p0, p1);
        pk[1] = (int)pkhu(p2, p3);
        *(int2v*)&Ps[wave][l15 * 72 + nc * 16 + quad * 4] = pk;
        float q0 = EXP2F(sB[nc][0]);
        float q1 = EXP2F(sB[nc][1]);
        float q2 = EXP2F(sB[nc][2]);
        float q3 = EXP2F(sB[nc][3]);
        laccB += (q0 + q1) + (q2 + q3);
        int2v pk2;
        pk2[0] = (int)pkhu(q0, q1);
        pk2[1] = (int)pkhu(q2, q3);
        *(int2v*)&Ps[wave][(16 + l15) * 72 + nc * 16 + quad * 4] = pk2;
      }
    } else {
      // ---- slow path: weights + mask (both groups) ----
      const int base_j = j0 + quad * 4;
#pragma unroll
      for (int nc = 0; nc < 4; ++nc) {
        const int jn = base_j + nc * 16;
        float pr[4], qr2[4];
#pragma unroll
        for (int r = 0; r < 4; ++r) {
          int dA = jn + r - bliA, d2A = jn + r - aliA;
          float eA  = (dA == 0) ? wblA : ((dA == widA) ? wbrA : 0.0f);
          float awA = (d2A == 0) ? a1A : ((d2A == 1) ? afrA : 0.0f);
          float vA = sA[nc][r] * (1.0f + eA + awA);
          vA = ((unsigned)dA <= widuA) ? vA : -115.0f;
          float pA = EXP2F(vA);
          laccA += pA;
          pr[r] = pA;
          int dB = jn + r - bliB, d2B = jn + r - aliB;
          float eB  = (dB == 0) ? wblB : ((dB == widB) ? wbrB : 0.0f);
          float awB = (d2B == 0) ? a1B : ((d2B == 1) ? afrB : 0.0f);
          float vB = sB[nc][r] * (1.0f + eB + awB);
          vB = ((unsigned)dB <= widuB) ? vB : -115.0f;
          float pB = EXP2F(vB);
          laccB += pB;
          qr2[r] = pB;
        }
        int2v pk;
        pk[0] = (int)pkhu(pr[0], pr[1]);
        pk[1] = (int)pkhu(pr[2], pr[3]);
        *(int2v*)&Ps[wave][l15 * 72 + nc * 16 + quad * 4] = pk;
        int2v pk2;
        pk2[0] = (int)pkhu(qr2[0], qr2[1]);
        pk2[1] = (int)pkhu(qr2[2], qr2[3]);
        *(int2v*)&Ps[wave][(16 + l15) * 72 + nc * 16 + quad * 4] = pk2;
      }
    }
    // wave-private Ps: no barrier needed

    // ---- O^T += V^T P^T (both groups share V b128 reads) ----
    bf16x8 bP0a = *(const bf16x8*)&Ps[wave][l15 * 72 + quad * 8];
    bf16x8 bP1a = *(const bf16x8*)&Ps[wave][l15 * 72 + 32 + quad * 8];
    bf16x8 bP0b = *(const bf16x8*)&Ps[wave][(16 + l15) * 72 + quad * 8];
    bf16x8 bP1b = *(const bf16x8*)&Ps[wave][(16 + l15) * 72 + 32 + quad * 8];
#pragma unroll
    for (int nc2 = 0; nc2 < 4; ++nc2) {
      const short* vb = &VtB[(nc2 * 16 + l15) * 72 + quad * 8];
      bf16x8 v0 = *(const bf16x8*)&vb[0];
      bf16x8 v1 = *(const bf16x8*)&vb[32];
      oA[nc2] = __builtin_amdgcn_mfma_f32_16x16x32_bf16(v0, bP0a, oA[nc2], 0, 0, 0);
      oA[nc2] = __builtin_amdgcn_mfma_f32_16x16x32_bf16(v1, bP1a, oA[nc2], 0, 0, 0);
      oB[nc2] = __builtin_amdgcn_mfma_f32_16x16x32_bf16(v0, bP0b, oB[nc2], 0, 0, 0);
      oB[nc2] = __builtin_amdgcn_mfma_f32_16x16x32_bf16(v1, bP1b, oB[nc2], 0, 0, 0);
    }

    // ---- write prefetched tile to alternate buffer; ONE barrier ----
    if (kt < kthi) {
      short* Kn = Ks[buf ^ 1];
      short* Vn = Vt[buf ^ 1];
      *(bf16x8*)&Kn[rq * 72 + cb] = kr0;
      *(bf16x8*)&Kn[(32 + rq) * 72 + cb] = kr1;
      *(bf16x8*)&Vn[rq * 72 + cb] = vr0;
      *(bf16x8*)&Vn[(32 + rq) * 72 + cb] = vr1;
      __syncthreads();
      buf ^= 1;
    }
  }

  // l: sum the 4 quads holding the same row
  laccA += __shfl_xor(laccA, 16);
  laccA += __shfl_xor(laccA, 32);
  laccB += __shfl_xor(laccB, 16);
  laccB += __shfl_xor(laccB, 32);
  if (lane < 16) {
    lpart[ks * NT + bh * T + ia] = laccA;
    lpart[ks * NT + bh * T + ib] = laccB;
  }

  // O^T epilogue (bf16): lane = row, regs = channels
  size_t obA = (size_t)ks * (B * T * E) + (size_t)(b * T + ia) * E + h * 64;
  size_t obB = (size_t)ks * (B * T * E) + (size_t)(b * T + ib) * E + h * 64;
#pragma unroll
  for (int nc2 = 0; nc2 < 4; ++nc2) {
    int2v pk;
    pk[0] = (int)pk2bf(oA[nc2][0], oA[nc2][1]);
    pk[1] = (int)pk2bf(oA[nc2][2], oA[nc2][3]);
    *(int2v*)&Opart[obA + nc2 * 16 + quad * 4] = pk;
    int2v pk2;
    pk2[0] = (int)pk2bf(oB[nc2][0], oB[nc2][1]);
    pk2[1] = (int)pk2bf(oB[nc2][2], oB[nc2][3]);
    *(int2v*)&Opart[obB + nc2 * 16 + quad * 4] = pk2;
  }
}

// =====================================================================
// attn = sum_s O_s / sum_s l_s, bf16 in/out. 8 elems/thread.
// =====================================================================
__global__ __launch_bounds__(256) void combine_attn(
    const short* __restrict__ Opart, const float* __restrict__ lpart,
    short* __restrict__ attnb)
{
  int base = (blockIdx.x * 256 + threadIdx.x) * 8;
  int row = base >> 9;            // / 512
  int c = base & 511;
  int h = c >> 6;
  int b = row >> 11;              // / T
  int i = row & (T - 1);
  int lidx = ((b << 3) + h) * T + i;
  float l = (lpart[lidx] + lpart[NT + lidx]) +
            (lpart[2 * NT + lidx] + lpart[3 * NT + lidx]);
  float inv = 1.0f / l;
  bf16x8 o0 = *(const bf16x8*)&Opart[base];
  bf16x8 o1 = *(const bf16x8*)&Opart[(size_t)(B * T * E) + base];
  bf16x8 o2 = *(const bf16x8*)&Opart[(size_t)(2 * B * T * E) + base];
  bf16x8 o3 = *(const bf16x8*)&Opart[(size_t)(3 * B * T * E) + base];
  int4v ov;
#pragma unroll
  for (int j = 0; j < 4; ++j) {
    float a = ((bf2f(o0[2 * j]) + bf2f(o1[2 * j])) +
               (bf2f(o2[2 * j]) + bf2f(o3[2 * j]))) * inv;
    float bb = ((bf2f(o0[2 * j + 1]) + bf2f(o1[2 * j + 1])) +
                (bf2f(o2[2 * j + 1]) + bf2f(o3[2 * j + 1]))) * inv;
    ov[j] = (int)pk2bf(a, bb);
  }
  *(int4v*)&attnb[base] = ov;
}

// =====================================================================
// out GEMM (bf16 MFMA): out[4096][512] = attnb @ w_out + b_out (fp32).
// Tile 64x64, BK=32, dbuf (1 barrier/iter). Grid (8, 64) = 512 blocks.
// =====================================================================
__global__ __launch_bounds__(256) void out_gemm_bf16(
    const short* __restrict__ Ab, const short* __restrict__ wT,
    const float* __restrict__ bias, float* __restrict__ Co)
{
  __shared__ __align__(16) short smem_o[10240];   // 2 bufs x (64*40 + 64*40)

  const int tid = threadIdx.x;
  const int wave = tid >> 6, lane = tid & 63;
  const int quad = lane >> 4, l15 = lane & 15;
  const int wm = wave >> 1, wn = wave & 1;
  const int m0 = blockIdx.y * 64, n0 = blockIdx.x * 64;

  f32x4 acc[2][2];
#pragma unroll
  for (int mi = 0; mi < 2; ++mi)
#pragma unroll
    for (int ni = 0; ni < 2; ++ni) acc[mi][ni] = (f32x4){0, 0, 0, 0};

  const int ar = tid >> 2, akc = (tid & 3) * 8;

#define OLD(R, K0) do {                                                  \
    R[0] = *(const bf16x8*)&Ab[(size_t)(m0 + ar) * 512 + (K0) + akc];    \
    R[1] = *(const bf16x8*)&wT[(size_t)(n0 + ar) * 512 + (K0) + akc];    \
  } while (0)
#define OST(BUF, R) do {                                                 \
    short* As_ = smem_o + (BUF) * 5120;                                  \
    short* Bt_ = As_ + 2560;                                             \
    *(bf16x8*)&As_[ar * 40 + akc] = R[0];                                \
    *(bf16x8*)&Bt_[ar * 40 + akc] = R[1];                                \
  } while (0)
#define OMM(BUF) do {                                                    \
    const short* As_ = smem_o + (BUF) * 5120;                            \
    const short* Bt_ = As_ + 2560;                                       \
    bf16x8 aA[2], bB[2];                                                 \
    for (int mi = 0; mi < 2; ++mi)                                       \
      aA[mi] = *(const bf16x8*)&As_[(wm * 32 + mi * 16 + l15) * 40 + quad * 8]; \
    for (int ni = 0; ni < 2; ++ni)                                       \
      bB[ni] = *(const bf16x8*)&Bt_[(wn * 32 + ni * 16 + l15) * 40 + quad * 8]; \
    for (int mi = 0; mi < 2; ++mi)                                       \
      for (int ni = 0; ni < 2; ++ni)                                     \
        acc[mi][ni] = __builtin_amdgcn_mfma_f32_16x16x32_bf16(           \
            aA[mi], bB[ni], acc[mi][ni], 0, 0, 0);                       \
  } while (0)

  bf16x8 rA[2], rB[2];
  OLD(rA, 0); OST(0, rA);
  OLD(rA, 32);
  __syncthreads();
#pragma unroll 1
  for (int k0 = 0; k0 < 512; k0 += 64) {
    if (k0 + 64 < 512) OLD(rB, k0 + 64);
    OMM(0);
    OST(1, rA);
    __syncthreads();
    if (k0 + 96 < 512) OLD(rA, k0 + 96);
    OMM(1);
    if (k0 + 64 < 512) { OST(0, rB); __syncthreads(); }
  }
#undef OLD
#undef OST
#undef OMM

#pragma unroll
  for (int mi = 0; mi < 2; ++mi)
#pragma unroll
    for (int ni = 0; ni < 2; ++ni)
#pragma unroll
      for (int r = 0; r < 4; ++r) {
        int row = m0 + wm * 32 + mi * 16 + quad * 4 + r;
        int col = n0 + wn * 32 + ni * 16 + l15;
        Co[(size_t)row * 512 + col] = acc[mi][ni][r] + bias[col];
      }
}

// =====================================================================
extern "C" void kernel_launch(void* const* d_in, const int* in_sizes, int n_in,
                              void* d_out, int out_size, void* d_ws, size_t ws_size,
                              hipStream_t stream)
{
  const float* x     = (const float*)d_in[0];
  const float* w_qkv = (const float*)d_in[1];
  const float* b_qkv = (const float*)d_in[2];
  const float* w_od  = (const float*)d_in[3];
  const float* b_od  = (const float*)d_in[4];
  const float* w_out = (const float*)d_in[5];
  const float* b_out = (const float*)d_in[6];
  float* out = (float*)d_out;

  char* w = (char*)d_ws;
  short* xb    = (short*)w;  w += (size_t)B * T * E * 2;           // 4 MB
  short* wTq   = (short*)w;  w += (size_t)E * 3 * E * 2;           // 1.5 MB
  short* wTo   = (short*)w;  w += (size_t)E * E * 2;               // 0.5 MB
  short* qkvb  = (short*)w;  w += (size_t)B * T * 3 * E * 2;       // 12.6 MB
  short* Vtg   = (short*)w;  w += (size_t)B * T * E * 2;           // 4 MB
  float* Wc    = (float*)w;  w += (size_t)E * 16 * 4;              // 32 KB
  float* bc    = (float*)w;  w += 256;
  float* prm   = (float*)w;  w += (size_t)7 * NT * 4;              // 896 KB
  short* Opart = (short*)w;  w += (size_t)KSPLIT * B * T * E * 2;  // 16.8 MB
  float* lpart = (float*)w;  w += (size_t)KSPLIT * NT * 4;         // 512 KB
  short* attnb = (short*)w;  w += (size_t)B * T * E * 2;           // 4 MB

  // 1) fused prep: casts + transposes + combined od weights
  prep_all<<<dim3(3105), 256, 0, stream>>>(
      x, w_qkv, b_qkv, w_od, b_od, xb, wTq, wTo, w_out, Wc, bc);

  // 2) fused qkv GEMM (V transposed, Q pre-scaled) + od/window params
  qkv_od<<<dim3(1024), 256, 0, stream>>>(
      xb, wTq, b_qkv, qkvb, Vtg, x, Wc, bc, prm);

  // 3) attention (128-q block, 2 q-groups/wave, K-split 4-way)
  flash_attn_mfma8<<<dim3(T / 128, BH, KSPLIT), 256, 0, stream>>>(
      qkvb, Vtg, prm, Opart, lpart);

  // 4) combine partials -> attn bf16
  combine_attn<<<dim3(B * T * E / 2048), 256, 0, stream>>>(Opart, lpart, attnb);

  // 5) out = attn @ w_out + b_out
  out_gemm_bf16<<<dim3(E / 64, B * T / 64), 256, 0, stream>>>(
      attnb, wTo, b_out, out);
}